// Round 1
// baseline (1451.350 us; speedup 1.0000x reference)
//
#include <hip/hip_runtime.h>

// EGAT simplification:
//   softmax over axis=1 of [E,1] == 1.0  =>  z = segment_sum(x[col], row) @ W.T
// Kernel 1: out[row[e]][:] += x[col[e]][:]   (float atomics, float4 loads)
// Kernel 2: out = out @ W.T  (in-place, per-16-row blocks, W staged in LDS)

__global__ __launch_bounds__(256) void egat_scatter(
    const float* __restrict__ x, const int* __restrict__ ei,
    float* __restrict__ out, int E)
{
    long tid = (long)blockIdx.x * blockDim.x + threadIdx.x;
    long e = tid >> 4;                 // 16 threads per edge
    if (e >= E) return;
    int c4 = (int)(tid & 15) << 2;     // channel group of 4
    int row = ei[e];                   // edge_index[0][e]
    int col = ei[(long)E + e];         // edge_index[1][e]
    const float4 v = *reinterpret_cast<const float4*>(x + (long)col * 64 + c4);
    float* o = out + (long)row * 64 + c4;
    atomicAdd(o + 0, v.x);
    atomicAdd(o + 1, v.y);
    atomicAdd(o + 2, v.z);
    atomicAdd(o + 3, v.w);
}

// In-place per-row transform: z[r][c] = sum_k A[r][k] * W[c][k]
__global__ __launch_bounds__(256) void egat_transform(
    float* __restrict__ out, const float* __restrict__ W, int N)
{
    __shared__ float a[16][64];
    __shared__ float w[64][65];        // +1 pad: (65c+k)%32 = (c+k)%32 -> 2-way only (free)
    int t = threadIdx.x;
    for (int i = t; i < 64 * 64; i += 256)
        w[i >> 6][i & 63] = W[i];
    long r0 = (long)blockIdx.x * 16;
    int c  = t & 63;
    int rb = t >> 6;                   // 0..3 (uniform within a wave)
    #pragma unroll
    for (int j = 0; j < 4; ++j) {
        long r = r0 + rb + 4 * j;
        if (r < N) a[rb + 4 * j][c] = out[r * 64 + c];
    }
    __syncthreads();
    float acc[4] = {0.f, 0.f, 0.f, 0.f};
    #pragma unroll
    for (int k = 0; k < 64; ++k) {
        float wk = w[c][k];
        #pragma unroll
        for (int j = 0; j < 4; ++j)
            acc[j] += a[rb + 4 * j][k] * wk;   // a[..][k] wave-uniform -> broadcast
    }
    #pragma unroll
    for (int j = 0; j < 4; ++j) {
        long r = r0 + rb + 4 * j;
        if (r < N) out[r * 64 + c] = acc[j];
    }
}

extern "C" void kernel_launch(void* const* d_in, const int* in_sizes, int n_in,
                              void* d_out, int out_size, void* d_ws, size_t ws_size,
                              hipStream_t stream)
{
    const float* x  = (const float*)d_in[0];   // [N, 64]
    const int*   ei = (const int*)d_in[1];     // [2, E] (harness delivers int32)
    const float* W  = (const float*)d_in[3];   // [64, 64]
    float* out = (float*)d_out;                // [N, 64]

    const int E = in_sizes[1] / 2;
    const int N = out_size / 64;

    hipMemsetAsync(out, 0, (size_t)N * 64 * sizeof(float), stream);

    long sthreads = (long)E * 16;
    int sgrid = (int)((sthreads + 255) / 256);
    egat_scatter<<<sgrid, 256, 0, stream>>>(x, ei, out, E);

    int tgrid = (N + 15) / 16;
    egat_transform<<<tgrid, 256, 0, stream>>>(out, W, N);
}

// Round 2
// 315.780 us; speedup vs baseline: 4.5961x; 4.5961x over previous
//
#include <hip/hip_runtime.h>

// z = segment_sum(x[col], row) @ W.T   (softmax over [E,1] axis=1 == 1)
// CSR build (int atomics only) + deterministic gather-sum + fused transform.

#define CHUNK 1024

__global__ __launch_bounds__(256) void k_hist(const int* __restrict__ ei,
                                              int* __restrict__ cnt, int E) {
    int e = blockIdx.x * 256 + threadIdx.x;
    if (e < E) atomicAdd(&cnt[ei[e]], 1);
}

__global__ __launch_bounds__(CHUNK) void k_reduce(const int* __restrict__ cnt,
                                                  int* __restrict__ psum, int N) {
    __shared__ int s[16];
    int i = blockIdx.x * CHUNK + threadIdx.x;
    int v = (i < N) ? cnt[i] : 0;
    for (int o = 32; o; o >>= 1) v += __shfl_down(v, o, 64);
    if ((threadIdx.x & 63) == 0) s[threadIdx.x >> 6] = v;
    __syncthreads();
    if (threadIdx.x < 16) {
        int t = s[threadIdx.x];
        for (int o = 8; o; o >>= 1) t += __shfl_down(t, o, 16);
        if (threadIdx.x == 0) psum[blockIdx.x] = t;
    }
}

// Exclusive scan of cnt -> off (N+1 entries) and cur (copy for the fill pass).
__global__ __launch_bounds__(CHUNK) void k_scan(const int* __restrict__ cnt,
                                                const int* __restrict__ psum,
                                                int* __restrict__ off,
                                                int* __restrict__ cur, int N) {
    __shared__ int s[CHUNK];
    __shared__ int base_s;
    int b = blockIdx.x;
    int i = b * CHUNK + threadIdx.x;
    int v = (i < N) ? cnt[i] : 0;
    s[threadIdx.x] = v;
    __syncthreads();
    for (int o = 1; o < CHUNK; o <<= 1) {
        int t = (threadIdx.x >= (unsigned)o) ? s[threadIdx.x - o] : 0;
        __syncthreads();
        s[threadIdx.x] += t;
        __syncthreads();
    }
    if (threadIdx.x < 64) {
        int t = 0;
        for (int j = threadIdx.x; j < b; j += 64) t += psum[j];
        for (int o = 32; o; o >>= 1) t += __shfl_down(t, o, 64);
        if (threadIdx.x == 0) base_s = t;
    }
    __syncthreads();
    int excl = base_s + s[threadIdx.x] - v;
    if (i <= N) off[i] = excl;     // off[N] == E
    if (i < N)  cur[i] = excl;
}

__global__ __launch_bounds__(256) void k_fill(const int* __restrict__ ei,
                                              int* __restrict__ cur,
                                              int* __restrict__ ccol, int E) {
    int e = blockIdx.x * 256 + threadIdx.x;
    if (e < E) {
        int r = ei[e];
        int c = ei[E + e];
        int p = atomicAdd(&cur[r], 1);
        ccol[p] = c;
    }
}

// Wave-per-node gather-sum, fused z = acc @ W.T via per-wave LDS broadcast.
__global__ __launch_bounds__(512) void k_gather(const float* __restrict__ x,
                                                const int* __restrict__ ccol,
                                                const int* __restrict__ off,
                                                const float* __restrict__ W,
                                                float* __restrict__ out, int N) {
    __shared__ float w[64][65];    // (65c+k)%32 = (c+k)%32 -> 2-way alias only (free)
    __shared__ float a_s[8][64];
    int t = threadIdx.x;
    for (int i = t; i < 64 * 64; i += 512) w[i >> 6][i & 63] = W[i];
    int lane = t & 63, wv = t >> 6;
    int n = blockIdx.x * 8 + wv;
    bool active = (n < N);
    int s = 0, e2 = 0;
    if (active) { s = off[n]; e2 = off[n + 1]; }
    float acc = 0.f;
    int j = s;
    for (; j + 4 <= e2; j += 4) {            // 4-way ILP on the latency chain
        int c0 = ccol[j], c1 = ccol[j + 1], c2 = ccol[j + 2], c3 = ccol[j + 3];
        float v0 = x[(long)c0 * 64 + lane];
        float v1 = x[(long)c1 * 64 + lane];
        float v2 = x[(long)c2 * 64 + lane];
        float v3 = x[(long)c3 * 64 + lane];
        acc += (v0 + v1) + (v2 + v3);
    }
    for (; j < e2; ++j) acc += x[(long)ccol[j] * 64 + lane];
    a_s[wv][lane] = acc;
    __syncthreads();                          // uniform: no early returns above
    float z = 0.f;
    #pragma unroll
    for (int k = 0; k < 64; ++k)
        z += a_s[wv][k] * w[lane][k];         // a_s[wv][k] wave-uniform -> broadcast
    if (active) out[(long)n * 64 + lane] = z;
}

// ---- fallback (R1 path) if workspace is too small ----
__global__ __launch_bounds__(256) void egat_scatter(const float* __restrict__ x,
                                                    const int* __restrict__ ei,
                                                    float* __restrict__ out, int E) {
    long tid = (long)blockIdx.x * blockDim.x + threadIdx.x;
    long e = tid >> 4;
    if (e >= E) return;
    int c4 = (int)(tid & 15) << 2;
    int row = ei[e];
    int col = ei[(long)E + e];
    const float4 v = *reinterpret_cast<const float4*>(x + (long)col * 64 + c4);
    float* o = out + (long)row * 64 + c4;
    atomicAdd(o + 0, v.x); atomicAdd(o + 1, v.y);
    atomicAdd(o + 2, v.z); atomicAdd(o + 3, v.w);
}

__global__ __launch_bounds__(256) void egat_transform(float* __restrict__ out,
                                                      const float* __restrict__ W, int N) {
    __shared__ float a[16][64];
    __shared__ float w[64][65];
    int t = threadIdx.x;
    for (int i = t; i < 64 * 64; i += 256) w[i >> 6][i & 63] = W[i];
    long r0 = (long)blockIdx.x * 16;
    int c = t & 63, rb = t >> 6;
    #pragma unroll
    for (int j = 0; j < 4; ++j) {
        long r = r0 + rb + 4 * j;
        if (r < N) a[rb + 4 * j][c] = out[r * 64 + c];
    }
    __syncthreads();
    float acc[4] = {0.f, 0.f, 0.f, 0.f};
    #pragma unroll
    for (int k = 0; k < 64; ++k) {
        float wk = w[c][k];
        #pragma unroll
        for (int j = 0; j < 4; ++j) acc[j] += a[rb + 4 * j][k] * wk;
    }
    #pragma unroll
    for (int j = 0; j < 4; ++j) {
        long r = r0 + rb + 4 * j;
        if (r < N) out[r * 64 + c] = acc[j];
    }
}

extern "C" void kernel_launch(void* const* d_in, const int* in_sizes, int n_in,
                              void* d_out, int out_size, void* d_ws, size_t ws_size,
                              hipStream_t stream)
{
    const float* x  = (const float*)d_in[0];
    const int*   ei = (const int*)d_in[1];
    const float* W  = (const float*)d_in[3];
    float* out = (float*)d_out;

    const int E = in_sizes[1] / 2;
    const int N = out_size / 64;
    const int nchunks = (N + 1 + CHUNK - 1) / CHUNK;

    // ws layout: cnt[N+1] | off[N+1] | cur[N] | psum[nchunks] | ccol[E]
    size_t need = ((size_t)(N + 1) * 2 + N + nchunks + E) * sizeof(int);
    if (ws_size >= need) {
        int* cnt  = (int*)d_ws;
        int* off  = cnt + (N + 1);
        int* cur  = off + (N + 1);
        int* psum = cur + N;
        int* ccol = psum + nchunks;

        hipMemsetAsync(cnt, 0, (size_t)(N + 1) * sizeof(int), stream);
        k_hist<<<(E + 255) / 256, 256, 0, stream>>>(ei, cnt, E);
        k_reduce<<<nchunks, CHUNK, 0, stream>>>(cnt, psum, N);
        k_scan<<<nchunks, CHUNK, 0, stream>>>(cnt, psum, off, cur, N);
        k_fill<<<(E + 255) / 256, 256, 0, stream>>>(ei, cur, ccol, E);
        k_gather<<<(N + 7) / 8, 512, 0, stream>>>(x, ccol, off, W, out, N);
    } else {
        hipMemsetAsync(out, 0, (size_t)N * 64 * sizeof(float), stream);
        long sthreads = (long)E * 16;
        egat_scatter<<<(int)((sthreads + 255) / 256), 256, 0, stream>>>(x, ei, out, E);
        egat_transform<<<(N + 15) / 16, 256, 0, stream>>>(out, W, N);
    }
}